// Round 4
// baseline (147.931 us; speedup 1.0000x reference)
//
#include <hip/hip_runtime.h>
#include <math.h>

// Second-order IIR (B=1024 rows, T=16384), fp32.
// V6: no register array lives across the scan (the V4/V5 spill bug).
// Pass 1 computes the zero-state chunk recurrence reading u from LDS and
// stores ONLY the 2-float chunk state; pass 3 re-reads u from LDS,
// recomputes v inline (3 FMA, bit-identical), applies the exact
// recurrence, and overwrites u with y in place. Only 2 scalars
// (um2s/um1s) cross the scan per thread.
// Staging: global_load_lds w=16, linear LDS dest + inverse-swizzled
// per-lane global source (rule #21); all LDS chunk traffic is
// conflict-free b128 via slot swizzle phys = s ^ ((s>>3)&7).
// Raw lgkm-only barriers; half-1 DMA issued before half-0 stores so
// vmcnt(8) at half-1 waits loads only.

#define TLEN  16384
#define HALF  8192
#define NT    256
#define CK    32
#define NCH   256
#define SCAN_OFF  8192                 // float index (u/y buf = 8192 floats)
#define CARRY_OFF (SCAN_OFF + 2*NCH)   // 8704
#define UH_OFF    (CARRY_OFF + 2)      // 8706: u[8190..8191] stash for h1 tid0
#define LDS_FLOATS (UH_OFF + 2)        // 8708 floats = 34832 B -> 4 blocks/CU

__device__ __forceinline__ int swz(int s) { return s ^ ((s >> 3) & 7); }

__device__ __forceinline__ void gll16(const float4* g, float4* l) {
    __builtin_amdgcn_global_load_lds(
        (const __attribute__((address_space(1))) unsigned int*)g,
        (__attribute__((address_space(3))) unsigned int*)l,
        16, 0, 0);
}

__device__ __forceinline__ void mat2_sq(float& m00, float& m01, float& m10, float& m11) {
    float t00 = m00*m00 + m01*m10;
    float t01 = m00*m01 + m01*m11;
    float t10 = m10*m00 + m11*m10;
    float t11 = m10*m01 + m11*m11;
    m00 = t00; m01 = t01; m10 = t10; m11 = t11;
}

// Raw barrier: orders LDS across the workgroup, does NOT drain vmcnt.
__device__ __forceinline__ void bar_lgkm() {
    asm volatile("s_waitcnt lgkmcnt(0)" ::: "memory");
    __builtin_amdgcn_s_barrier();
    __builtin_amdgcn_sched_barrier(0);
}

__global__ __launch_bounds__(NT, 4)
void iir_kernel(const float* __restrict__ bc,
                const float* __restrict__ rho_p,
                const float* __restrict__ psi_p,
                const float* __restrict__ u_in,
                const float* __restrict__ y_init,
                const float* __restrict__ u_init,
                float* __restrict__ y_out)
{
    __shared__ float lds[LDS_FLOATS];
    float4* lds4 = (float4*)lds;
    const int row = blockIdx.x;
    const int tid = threadIdx.x;
    const int xr  = tid & 7;

    const float*  urow = u_in  + (size_t)row * TLEN;
    float*        orow = y_out + (size_t)row * TLEN;
    const float4* up   = (const float4*)urow;

    // ---- issue half-0 staging immediately: linear LDS dest, swizzled src ----
    #pragma unroll
    for (int k = 0; k < 8; ++k) {
        int p = k * NT + tid;
        gll16(up + swz(p), lds4 + p);
    }
    __builtin_amdgcn_sched_barrier(0);

    // scalar params (overlap the DMA)
    float2 ui = *(const float2*)&u_init[2*row];   // (u_init[:,0], u_init[:,1])
    const float rho = rho_p[0];
    const float psi = psi_p[0];
    const float r   = 1.0f / (1.0f + expf(-rho));
    const float th  = 3.14159265358979323846f / (1.0f + expf(-psi));
    const float a1  = -2.0f * r * cosf(th);
    const float a2  = r * r;
    const float b0  = bc[0], b1 = bc[1], b2 = bc[2];

    #pragma unroll
    for (int h = 0; h < 2; ++h) {
        // ---- wait this half's staging: h0 all; h1 loads only (8 stores newer) ----
        if (h == 0) asm volatile("s_waitcnt vmcnt(0)" ::: "memory");
        else        asm volatile("s_waitcnt vmcnt(8)" ::: "memory");
        __builtin_amdgcn_s_barrier();
        __builtin_amdgcn_sched_barrier(0);

        // ---- pass 1: zero-state chunk recurrence (reads u, stores state only) ----
        float um2, um1;
        if (tid == 0) {
            if (h == 0) { um2 = ui.y; um1 = ui.x; }   // u_ext[0]=u_init[:,1], [1]=u_init[:,0]
            else        { um2 = lds[UH_OFF]; um1 = lds[UH_OFF + 1]; }
        } else {
            int hq = swz(8*tid - 1);                  // slot with u[32t-4..32t-1]
            float2 hh = *(const float2*)&lds[4*hq + 2];
            um2 = hh.x; um1 = hh.y;
        }
        const float um2s = um2, um1s = um1;           // ONLY state crossing the scan

        float y1 = 0.0f, y2 = 0.0f;
        #pragma unroll
        for (int q = 0; q < 8; ++q) {
            float4 u4 = lds4[8*tid + (q ^ xr)];
            #define STEP(UC) {                                          \
                float uc_ = (UC);                                       \
                float vv_ = fmaf(b2, um2, fmaf(b1, um1, b0 * uc_));     \
                float y_  = fmaf(-a1, y1, fmaf(-a2, y2, vv_));          \
                y2 = y1; y1 = y_;                                       \
                um2 = um1; um1 = uc_; }
            STEP(u4.x); STEP(u4.y); STEP(u4.z); STEP(u4.w);
            #undef STEP
        }
        *(float2*)&lds[SCAN_OFF + 2*tid] = make_float2(y1, y2);
        if (h == 0 && tid == NT - 1) {                // u[8190], u[8191] for h1 tid0
            lds[UH_OFF]     = um2;
            lds[UH_OFF + 1] = um1;
        }
        bar_lgkm();                                   // states (+stash) visible

        // ---- wave-0 affine scan over 256 chunk states ----
        if (tid < 64) {
            const int l = tid;
            float m00 = -a1, m01 = -a2, m10 = 1.0f, m11 = 0.0f;
            #pragma unroll
            for (int s = 0; s < 5; ++s) mat2_sq(m00, m01, m10, m11);  // A^32

            float4 q0 = *(const float4*)&lds[SCAN_OFF + 8*l];
            float4 q1 = *(const float4*)&lds[SCAN_OFF + 8*l + 4];
            float da[4] = {q0.x, q0.z, q1.x, q1.z};
            float db[4] = {q0.y, q0.w, q1.y, q1.w};

            float seed0 = 0.0f, seed1 = 0.0f;
            if (l == 0) {
                if (h == 0) { seed0 = y_init[2*row]; seed1 = y_init[2*row + 1]; }
                else        { seed0 = lds[CARRY_OFF]; seed1 = lds[CARRY_OFF + 1]; }
            }
            float s0 = seed0, s1 = seed1;
            #pragma unroll
            for (int m = 0; m < 4; ++m) {
                float n0 = fmaf(m00, s0, fmaf(m01, s1, da[m]));
                float n1 = fmaf(m10, s0, fmaf(m11, s1, db[m]));
                s0 = n0; s1 = n1;
            }
            float w00 = m00, w01 = m01, w10 = m10, w11 = m11;
            mat2_sq(w00, w01, w10, w11);
            mat2_sq(w00, w01, w10, w11);              // W = M^4
            #pragma unroll
            for (int p = 0; p < 6; ++p) {
                float o0 = __shfl_up(s0, 1 << p);
                float o1 = __shfl_up(s1, 1 << p);
                if (l >= (1 << p)) {
                    s0 = fmaf(w00, o0, fmaf(w01, o1, s0));
                    s1 = fmaf(w10, o0, fmaf(w11, o1, s1));
                }
                if (p < 5) mat2_sq(w00, w01, w10, w11);
            }
            float p0 = __shfl_up(s0, 1);
            float p1 = __shfl_up(s1, 1);
            if (l == 0) { p0 = seed0; p1 = seed1; }
            float c0 = p0, c1 = p1;
            #pragma unroll
            for (int m = 0; m < 4; ++m) {
                *(float2*)&lds[SCAN_OFF + 2*(4*l + m)] = make_float2(c0, c1);
                float n0 = fmaf(m00, c0, fmaf(m01, c1, da[m]));
                float n1 = fmaf(m10, c0, fmaf(m11, c1, db[m]));
                c0 = n0; c1 = n1;
            }
            if (l == 63 && h == 0) {                  // exact carry into half 1
                lds[CARRY_OFF]     = c0;
                lds[CARRY_OFF + 1] = c1;
            }
        }
        bar_lgkm();

        // ---- pass 3: re-read u, recompute v inline, exact recurrence, y in place ----
        {
            float2 inc = *(const float2*)&lds[SCAN_OFF + 2*tid];
            float y1f = inc.x, y2f = inc.y;
            float m2 = um2s, m1 = um1s;
            #pragma unroll
            for (int q = 0; q < 8; ++q) {
                int s = 8*tid + (q ^ xr);
                float4 u4 = lds4[s];
                float va = fmaf(b2, m2,   fmaf(b1, m1,   b0 * u4.x));
                float ya = fmaf(-a1, y1f, fmaf(-a2, y2f, va));
                float vb = fmaf(b2, m1,   fmaf(b1, u4.x, b0 * u4.y));
                float yb = fmaf(-a1, ya,  fmaf(-a2, y1f, vb));
                float vc = fmaf(b2, u4.x, fmaf(b1, u4.y, b0 * u4.z));
                float yc = fmaf(-a1, yb,  fmaf(-a2, ya,  vc));
                float vd = fmaf(b2, u4.y, fmaf(b1, u4.z, b0 * u4.w));
                float yd = fmaf(-a1, yc,  fmaf(-a2, yb,  vd));
                float4 w; w.x = ya; w.y = yb; w.z = yc; w.w = yd;
                lds4[s] = w;                          // in-thread read->write, dep-ordered
                m2 = u4.z; m1 = u4.w;
                y2f = yc; y1f = yd;
            }
        }
        bar_lgkm();                                   // all y visible

        // ---- drain: LDS -> regs; (h0) issue half-1 DMA; then stores ----
        float4 yreg[8];
        #pragma unroll
        for (int k = 0; k < 8; ++k) yreg[k] = lds4[swz(k * NT + tid)];
        asm volatile("s_waitcnt lgkmcnt(0)" ::: "memory");

        if (h == 0) {
            __builtin_amdgcn_s_barrier();             // everyone's drain reads done
            __builtin_amdgcn_sched_barrier(0);
            #pragma unroll
            for (int k = 0; k < 8; ++k) {             // half-1 staging (clobbers buffer)
                int p = k * NT + tid;
                gll16(up + (HALF/4) + swz(p), lds4 + p);
            }
            __builtin_amdgcn_sched_barrier(0);        // keep loads BEFORE stores
        }

        float4* op = (float4*)(orow + h * HALF);
        #pragma unroll
        for (int k = 0; k < 8; ++k) op[k * NT + tid] = yreg[k];  // fire-and-forget
        __builtin_amdgcn_sched_barrier(0);
    }
}

extern "C" void kernel_launch(void* const* d_in, const int* in_sizes, int n_in,
                              void* d_out, int out_size, void* d_ws, size_t ws_size,
                              hipStream_t stream) {
    const float* bc    = (const float*)d_in[0];
    const float* rho   = (const float*)d_in[1];
    const float* psi   = (const float*)d_in[2];
    const float* u_in  = (const float*)d_in[3];
    const float* y_in  = (const float*)d_in[4];
    const float* u_ini = (const float*)d_in[5];
    float* y = (float*)d_out;
    const int B = in_sizes[3] / TLEN;     // 1024
    iir_kernel<<<B, NT, 0, stream>>>(bc, rho, psi, u_in, y_in, u_ini, y);
}

// Round 6
// 123.762 us; speedup vs baseline: 1.1953x; 1.1953x over previous
//
#include <hip/hip_runtime.h>
#include <math.h>

// Second-order IIR (B=1024 rows, T=16384), fp32.
// V7 (resubmit after infra flake): V6's data path with ZERO inline asm —
// plain __syncthreads() only, compiler-managed waitcnt/scheduling
// (m141 lesson: sched_barrier(0) pinning defeats the scheduler;
// V2's asm-free 41us vs V4-V6's 50-52us).
//
// Data path (correctness-proven in V5/V6):
//  - global_load_lds w=16 staging: linear LDS dest + inverse-swizzled
//    per-lane global source (rule #21), zero staging VGPRs.
//  - LDS float4-slot swizzle phys = s ^ ((s>>3)&7) (self-inverse):
//    both lane-interleaved (stage/drain) and per-thread-chunk
//    (pass1/pass3) b128 accesses are bank-balanced.
//  - Pass 1 computes the zero-state chunk recurrence reading u from LDS,
//    stores only the 2-float chunk state (nothing big crosses the scan).
//  - Wave-0 affine scan (2x2 matrix Kogge-Stone over 256 chunk states).
//  - Pass 3 re-reads u, recomputes v inline (bit-identical FMAs),
//    applies the exact recurrence, overwrites u with y in place.
//  - Drain: plain coalesced-store loop (compiler pipelines it).

#define TLEN  16384
#define HALF  8192
#define NT    256
#define CK    32
#define NCH   256
#define SCAN_OFF  8192                 // float index (u/y buf = 8192 floats)
#define CARRY_OFF (SCAN_OFF + 2*NCH)   // 8704
#define UH_OFF    (CARRY_OFF + 2)      // 8706: u[8190..8191] stash for h1 tid0
#define LDS_FLOATS (UH_OFF + 2)        // 8708 floats = 34832 B -> 4 blocks/CU

__device__ __forceinline__ int swz(int s) { return s ^ ((s >> 3) & 7); }

__device__ __forceinline__ void gll16(const float4* g, float4* l) {
    __builtin_amdgcn_global_load_lds(
        (const __attribute__((address_space(1))) unsigned int*)g,
        (__attribute__((address_space(3))) unsigned int*)l,
        16, 0, 0);
}

__device__ __forceinline__ void mat2_sq(float& m00, float& m01, float& m10, float& m11) {
    float t00 = m00*m00 + m01*m10;
    float t01 = m00*m01 + m01*m11;
    float t10 = m10*m00 + m11*m10;
    float t11 = m10*m01 + m11*m11;
    m00 = t00; m01 = t01; m10 = t10; m11 = t11;
}

__global__ __launch_bounds__(NT, 4)
void iir_kernel(const float* __restrict__ bc,
                const float* __restrict__ rho_p,
                const float* __restrict__ psi_p,
                const float* __restrict__ u_in,
                const float* __restrict__ y_init,
                const float* __restrict__ u_init,
                float* __restrict__ y_out)
{
    __shared__ float lds[LDS_FLOATS];
    float4* lds4 = (float4*)lds;
    const int row = blockIdx.x;
    const int tid = threadIdx.x;
    const int xr  = tid & 7;

    const float*  urow = u_in  + (size_t)row * TLEN;
    float*        orow = y_out + (size_t)row * TLEN;
    const float4* up   = (const float4*)urow;

    // ---- issue half-0 staging: linear LDS dest, swizzled global src ----
    #pragma unroll
    for (int k = 0; k < 8; ++k) {
        int p = k * NT + tid;
        gll16(up + swz(p), lds4 + p);
    }

    // scalar params (overlap the DMA)
    float2 ui = *(const float2*)&u_init[2*row];   // (u_init[:,0], u_init[:,1])
    const float rho = rho_p[0];
    const float psi = psi_p[0];
    const float r   = 1.0f / (1.0f + expf(-rho));
    const float th  = 3.14159265358979323846f / (1.0f + expf(-psi));
    const float a1  = -2.0f * r * cosf(th);
    const float a2  = r * r;
    const float b0  = bc[0], b1 = bc[1], b2 = bc[2];

    #pragma unroll 1
    for (int h = 0; h < 2; ++h) {
        __syncthreads();                              // staging complete (drains DMA)

        // ---- pass 1: zero-state chunk recurrence (reads u, stores state only) ----
        float um2, um1;
        if (tid == 0) {
            if (h == 0) { um2 = ui.y; um1 = ui.x; }   // u_ext[0]=u_init[:,1], [1]=u_init[:,0]
            else        { um2 = lds[UH_OFF]; um1 = lds[UH_OFF + 1]; }
        } else {
            int hq = swz(8*tid - 1);                  // slot with u[32t-4..32t-1]
            float2 hh = *(const float2*)&lds[4*hq + 2];
            um2 = hh.x; um1 = hh.y;
        }
        const float um2s = um2, um1s = um1;           // ONLY state crossing the scan

        float y1 = 0.0f, y2 = 0.0f;
        #pragma unroll
        for (int q = 0; q < 8; ++q) {
            float4 u4 = lds4[8*tid + (q ^ xr)];
            #define STEP(UC) {                                          \
                float uc_ = (UC);                                       \
                float vv_ = fmaf(b2, um2, fmaf(b1, um1, b0 * uc_));     \
                float y_  = fmaf(-a1, y1, fmaf(-a2, y2, vv_));          \
                y2 = y1; y1 = y_;                                       \
                um2 = um1; um1 = uc_; }
            STEP(u4.x); STEP(u4.y); STEP(u4.z); STEP(u4.w);
            #undef STEP
        }
        *(float2*)&lds[SCAN_OFF + 2*tid] = make_float2(y1, y2);
        if (h == 0 && tid == NT - 1) {                // u[8190], u[8191] for h1 tid0
            lds[UH_OFF]     = um2;
            lds[UH_OFF + 1] = um1;
        }
        __syncthreads();                              // states (+stash) visible

        // ---- wave-0 affine scan over 256 chunk states ----
        if (tid < 64) {
            const int l = tid;
            float m00 = -a1, m01 = -a2, m10 = 1.0f, m11 = 0.0f;
            #pragma unroll
            for (int s = 0; s < 5; ++s) mat2_sq(m00, m01, m10, m11);  // A^32

            float4 q0 = *(const float4*)&lds[SCAN_OFF + 8*l];
            float4 q1 = *(const float4*)&lds[SCAN_OFF + 8*l + 4];
            float da[4] = {q0.x, q0.z, q1.x, q1.z};
            float db[4] = {q0.y, q0.w, q1.y, q1.w};

            float seed0 = 0.0f, seed1 = 0.0f;
            if (l == 0) {
                if (h == 0) { seed0 = y_init[2*row]; seed1 = y_init[2*row + 1]; }
                else        { seed0 = lds[CARRY_OFF]; seed1 = lds[CARRY_OFF + 1]; }
            }
            float s0 = seed0, s1 = seed1;
            #pragma unroll
            for (int m = 0; m < 4; ++m) {
                float n0 = fmaf(m00, s0, fmaf(m01, s1, da[m]));
                float n1 = fmaf(m10, s0, fmaf(m11, s1, db[m]));
                s0 = n0; s1 = n1;
            }
            float w00 = m00, w01 = m01, w10 = m10, w11 = m11;
            mat2_sq(w00, w01, w10, w11);
            mat2_sq(w00, w01, w10, w11);              // W = M^4
            #pragma unroll
            for (int p = 0; p < 6; ++p) {
                float o0 = __shfl_up(s0, 1 << p);
                float o1 = __shfl_up(s1, 1 << p);
                if (l >= (1 << p)) {
                    s0 = fmaf(w00, o0, fmaf(w01, o1, s0));
                    s1 = fmaf(w10, o0, fmaf(w11, o1, s1));
                }
                if (p < 5) mat2_sq(w00, w01, w10, w11);
            }
            float p0 = __shfl_up(s0, 1);
            float p1 = __shfl_up(s1, 1);
            if (l == 0) { p0 = seed0; p1 = seed1; }
            float c0 = p0, c1 = p1;
            #pragma unroll
            for (int m = 0; m < 4; ++m) {
                *(float2*)&lds[SCAN_OFF + 2*(4*l + m)] = make_float2(c0, c1);
                float n0 = fmaf(m00, c0, fmaf(m01, c1, da[m]));
                float n1 = fmaf(m10, c0, fmaf(m11, c1, db[m]));
                c0 = n0; c1 = n1;
            }
            if (l == 63 && h == 0) {                  // exact carry into half 1
                lds[CARRY_OFF]     = c0;
                lds[CARRY_OFF + 1] = c1;
            }
        }
        __syncthreads();

        // ---- pass 3: re-read u, recompute v inline, exact recurrence, y in place ----
        {
            float2 inc = *(const float2*)&lds[SCAN_OFF + 2*tid];
            float y1f = inc.x, y2f = inc.y;
            float m2 = um2s, m1 = um1s;
            #pragma unroll
            for (int q = 0; q < 8; ++q) {
                int s = 8*tid + (q ^ xr);
                float4 u4 = lds4[s];
                float va = fmaf(b2, m2,   fmaf(b1, m1,   b0 * u4.x));
                float ya = fmaf(-a1, y1f, fmaf(-a2, y2f, va));
                float vb = fmaf(b2, m1,   fmaf(b1, u4.x, b0 * u4.y));
                float yb = fmaf(-a1, ya,  fmaf(-a2, y1f, vb));
                float vc = fmaf(b2, u4.x, fmaf(b1, u4.y, b0 * u4.z));
                float yc = fmaf(-a1, yb,  fmaf(-a2, ya,  vc));
                float vd = fmaf(b2, u4.y, fmaf(b1, u4.z, b0 * u4.w));
                float yd = fmaf(-a1, yc,  fmaf(-a2, yb,  vd));
                float4 w; w.x = ya; w.y = yb; w.z = yc; w.w = yd;
                lds4[s] = w;                          // in-thread read->write, dep-ordered
                m2 = u4.z; m1 = u4.w;
                y2f = yc; y1f = yd;
            }
        }
        __syncthreads();                              // all y visible

        // ---- drain: LDS -> global, coalesced; compiler pipelines this loop ----
        float4* op = (float4*)(orow + h * HALF);
        #pragma unroll
        for (int k = 0; k < 8; ++k) {
            int g = k * NT + tid;
            op[g] = lds4[swz(g)];
        }

        // ---- issue half-1 staging (buffer clobber: after everyone's drain) ----
        if (h == 0) {
            __syncthreads();
            #pragma unroll
            for (int k = 0; k < 8; ++k) {
                int p = k * NT + tid;
                gll16(up + (HALF/4) + swz(p), lds4 + p);
            }
        }
    }
}

extern "C" void kernel_launch(void* const* d_in, const int* in_sizes, int n_in,
                              void* d_out, int out_size, void* d_ws, size_t ws_size,
                              hipStream_t stream) {
    const float* bc    = (const float*)d_in[0];
    const float* rho   = (const float*)d_in[1];
    const float* psi   = (const float*)d_in[2];
    const float* u_in  = (const float*)d_in[3];
    const float* y_in  = (const float*)d_in[4];
    const float* u_ini = (const float*)d_in[5];
    float* y = (float*)d_out;
    const int B = in_sizes[3] / TLEN;     // 1024
    iir_kernel<<<B, NT, 0, stream>>>(bc, rho, psi, u_in, y_in, u_ini, y);
}